// Round 9
// baseline (553.306 us; speedup 1.0000x reference)
//
#include <hip/hip_runtime.h>
#include <math.h>

#define Nn 100000
#define Cc 256
#define Dd 32
#define Hh 8
#define SEMk 128
#define PAD 32
#define NEG 0.2f
#define NB1 25000          // k_gat blocks per layer (4 nodes/block)
#define NTASK 12500        // k_score wave-tasks total (6250 per layer)

#if __has_builtin(__builtin_amdgcn_exp2f)
#define EXP2(x) __builtin_amdgcn_exp2f(x)
#else
#define EXP2(x) exp2f(x)
#endif
#define LOG2E 1.44269504088896f

typedef __attribute__((ext_vector_type(8))) short bf16x8;
typedef __attribute__((ext_vector_type(4))) short s16x4;
typedef __attribute__((ext_vector_type(4))) float f32x4;

__device__ __forceinline__ short f2bf(float f) {
    unsigned u = __float_as_uint(f);
    u = (u + 0x7FFF + ((u >> 16) & 1)) >> 16;   // round-to-nearest-even
    return (short)u;
}

// K3+K0: edge scatter for BOTH layers + (Wt transpose, fcwb convert) folded in.
__global__ __launch_bounds__(256) void k_scatter(const int* __restrict__ ei1, int E1,
                                                 const int* __restrict__ ei2, int E2,
                                                 int* __restrict__ cnt,
                                                 int* __restrict__ slt1,
                                                 int* __restrict__ slt2,
                                                 const float* __restrict__ W,
                                                 float* __restrict__ Wt,
                                                 const float* __restrict__ fcw,
                                                 short* __restrict__ fcwb) {
    int id = blockIdx.x * 256 + threadIdx.x;
    if (id < SEMk * Cc) {               // prep work rides on the first blocks
        if (id < Dd * Cc) {
            int j = id >> 5, k = id & 31;
            Wt[id] = W[k * Cc + j];
        }
        fcwb[id] = f2bf(fcw[id]);
    }
    const int* ei; int e, EE; int* c; int* sl;
    if (id < E1) { ei = ei1; e = id; EE = E1; c = cnt; sl = slt1; }
    else {
        e = id - E1;
        if (e >= E2) return;
        ei = ei2; EE = E2; c = cnt + Nn; sl = slt2;
    }
    int s = ei[e];
    int d = ei[EE + e];
    int pos = atomicAdd(&c[d], 1);
    if (pos < PAD) sl[d * PAD + pos] = s;
}

// K1: h = x @ W^T + per-node attention projections, 2 nodes/thread.
// 128 thr = 2 waves, 32 nodes/block. W LDS-reads amortized over 2 nodes
// (1.67x less LDS traffic than 1 node/thread). Scores pre-scaled by log2e
// so k_gat uses bare v_exp_f32: exp(leaky(d+s)) == 2^(leaky(L*d+L*s)).
__global__ __launch_bounds__(128) void k_hproj(const float* __restrict__ x,
                                               const float* __restrict__ Wt,
                                               const float* __restrict__ att1,
                                               const float* __restrict__ att2,
                                               float* __restrict__ h,
                                               float* __restrict__ sd1, float* __restrict__ ss1,
                                               float* __restrict__ sd2, float* __restrict__ ss2) {
    __shared__ float4 xs[32 * 65];
    __shared__ float  wt[256 * 36];
    __shared__ float4 hs[32 * 9];
    __shared__ float  a1[8 * 68];
    __shared__ float  a2[8 * 68];

    int t = threadIdx.x;
    int nb = blockIdx.x * 32;

    const float4* xg = (const float4*)x + (size_t)nb * 64;
#pragma unroll
    for (int it = 0; it < 16; ++it) {
        int i = t + it * 128;
        xs[(i >> 6) * 65 + (i & 63)] = xg[i];
    }
    const float4* wg = (const float4*)Wt;
#pragma unroll
    for (int it = 0; it < 16; ++it) {
        int i = t + it * 128;
        *(float4*)&wt[(i >> 3) * 36 + (i & 7) * 4] = wg[i];
    }
#pragma unroll
    for (int it = 0; it < 4; ++it) {
        int i = t + it * 128;
        a1[(i >> 6) * 68 + (i & 63)] = att1[i];
        a2[(i >> 6) * 68 + (i & 63)] = att2[i];
    }
    __syncthreads();

    int np = t >> 3;                   // 0..15 -> nodes 2np, 2np+1
    int dq = t & 7;
    int n0 = np * 2, n1 = n0 + 1;
    float4 acc0 = make_float4(0.f, 0.f, 0.f, 0.f);
    float4 acc1 = make_float4(0.f, 0.f, 0.f, 0.f);
    const float4* xr0 = &xs[n0 * 65];
    const float4* xr1 = &xs[n1 * 65];
#pragma unroll 4
    for (int j4 = 0; j4 < 64; ++j4) {
        float4 xv0 = xr0[j4];
        float4 xv1 = xr1[j4];
        float4 w0 = *(const float4*)&wt[(j4 * 4 + 0) * 36 + dq * 4];
        float4 w1 = *(const float4*)&wt[(j4 * 4 + 1) * 36 + dq * 4];
        float4 w2 = *(const float4*)&wt[(j4 * 4 + 2) * 36 + dq * 4];
        float4 w3 = *(const float4*)&wt[(j4 * 4 + 3) * 36 + dq * 4];
        acc0.x += xv0.x * w0.x + xv0.y * w1.x + xv0.z * w2.x + xv0.w * w3.x;
        acc0.y += xv0.x * w0.y + xv0.y * w1.y + xv0.z * w2.y + xv0.w * w3.y;
        acc0.z += xv0.x * w0.z + xv0.y * w1.z + xv0.z * w2.z + xv0.w * w3.z;
        acc0.w += xv0.x * w0.w + xv0.y * w1.w + xv0.z * w2.w + xv0.w * w3.w;
        acc1.x += xv1.x * w0.x + xv1.y * w1.x + xv1.z * w2.x + xv1.w * w3.x;
        acc1.y += xv1.x * w0.y + xv1.y * w1.y + xv1.z * w2.y + xv1.w * w3.y;
        acc1.z += xv1.x * w0.z + xv1.y * w1.z + xv1.z * w2.z + xv1.w * w3.z;
        acc1.w += xv1.x * w0.w + xv1.y * w1.w + xv1.z * w2.w + xv1.w * w3.w;
    }
    ((float4*)h)[(size_t)(nb + n0) * 8 + dq] = acc0;
    ((float4*)h)[(size_t)(nb + n1) * 8 + dq] = acc1;
    hs[n0 * 9 + dq] = acc0;
    hs[n1 * 9 + dq] = acc1;
    __syncthreads();

    int hh = t & 7;
#pragma unroll
    for (int rep = 0; rep < 2; ++rep) {
        int nl2 = (t >> 3) * 2 + rep;
        float d1 = 0.f, s1 = 0.f, d2 = 0.f, s2 = 0.f;
#pragma unroll
        for (int d4 = 0; d4 < 8; ++d4) {
            float4 hv = hs[nl2 * 9 + d4];
            float4 ad1 = *(const float4*)&a1[hh * 68 + d4 * 4];
            float4 as1 = *(const float4*)&a1[hh * 68 + 32 + d4 * 4];
            float4 ad2 = *(const float4*)&a2[hh * 68 + d4 * 4];
            float4 as2 = *(const float4*)&a2[hh * 68 + 32 + d4 * 4];
            d1 += hv.x * ad1.x + hv.y * ad1.y + hv.z * ad1.z + hv.w * ad1.w;
            s1 += hv.x * as1.x + hv.y * as1.y + hv.z * as1.z + hv.w * as1.w;
            d2 += hv.x * ad2.x + hv.y * ad2.y + hv.z * ad2.z + hv.w * ad2.w;
            s2 += hv.x * as2.x + hv.y * as2.y + hv.z * as2.z + hv.w * as2.w;
        }
        int n = nb + nl2;
        sd1[n * 8 + hh] = d1 * LOG2E; ss1[n * 8 + hh] = s1 * LOG2E;
        sd2[n * 8 + hh] = d2 * LOG2E; ss2[n * 8 + hh] = s2 * LOG2E;
    }
}

// ---- gat helper macros: readlane (uniform slot index -> SGPR base, saddr
// loads, zero VALU addressing) ----
#define LOADC(S0,S1,S2,S3,A0,A1,A2,A3,V0,V1,V2,V3,BB) do {                         \
    S0 = __builtin_amdgcn_readlane(sval, (BB) + 0);                                \
    S1 = __builtin_amdgcn_readlane(sval, (BB) + 1);                                \
    S2 = __builtin_amdgcn_readlane(sval, (BB) + 2);                                \
    S3 = __builtin_amdgcn_readlane(sval, (BB) + 3);                                \
    S1 = ((BB) + 1 < deg) ? S1 : n;                                                \
    S2 = ((BB) + 2 < deg) ? S2 : n;                                                \
    S3 = ((BB) + 3 < deg) ? S3 : n;                                                \
    A0 = ssrc[(unsigned)S0 * 8u + hh]; A1 = ssrc[(unsigned)S1 * 8u + hh];          \
    A2 = ssrc[(unsigned)S2 * 8u + hh]; A3 = ssrc[(unsigned)S3 * 8u + hh];          \
    V0 = h4[(unsigned)S0 * 8u + sub];  V1 = h4[(unsigned)S1 * 8u + sub];           \
    V2 = h4[(unsigned)S2 * 8u + sub];  V3 = h4[(unsigned)S3 * 8u + sub];           \
} while (0)

#define CONS(A0,A1,A2,A3,V0,V1,V2,V3,BB) do {                                      \
    float ev_, w_;                                                                 \
    ev_ = sd + A0; ev_ = ev_ > 0.f ? ev_ : NEG * ev_; w_ = EXP2(ev_);              \
    acc.x += w_ * V0.x; acc.y += w_ * V0.y; acc.z += w_ * V0.z; acc.w += w_ * V0.w; ssum += w_; \
    ev_ = sd + A1; ev_ = ev_ > 0.f ? ev_ : NEG * ev_; w_ = EXP2(ev_);              \
    w_ = ((BB) + 1 < deg) ? w_ : 0.f;                                              \
    acc.x += w_ * V1.x; acc.y += w_ * V1.y; acc.z += w_ * V1.z; acc.w += w_ * V1.w; ssum += w_; \
    ev_ = sd + A2; ev_ = ev_ > 0.f ? ev_ : NEG * ev_; w_ = EXP2(ev_);              \
    w_ = ((BB) + 2 < deg) ? w_ : 0.f;                                              \
    acc.x += w_ * V2.x; acc.y += w_ * V2.y; acc.z += w_ * V2.z; acc.w += w_ * V2.w; ssum += w_; \
    ev_ = sd + A3; ev_ = ev_ > 0.f ? ev_ : NEG * ev_; w_ = EXP2(ev_);              \
    w_ = ((BB) + 3 < deg) ? w_ : 0.f;                                              \
    acc.x += w_ * V3.x; acc.y += w_ * V3.y; acc.z += w_ * V3.z; acc.w += w_ * V3.w; ssum += w_; \
} while (0)

// K4: GAT layer, both layers in ONE launch (block range selects layer).
// One wave per node; chunk-4 ping-pong pipeline with SGPR-base gathers.
__global__ __launch_bounds__(256, 4) void k_gat(const float* __restrict__ h,
                                                const float* __restrict__ sd1, const float* __restrict__ ss1,
                                                const float* __restrict__ sd2, const float* __restrict__ ss2,
                                                const int* __restrict__ cnt,
                                                const int* __restrict__ slt1, const int* __restrict__ slt2,
                                                float* __restrict__ Z1, float* __restrict__ Z2) {
    int blk = blockIdx.x;
    const float* sdst = sd1; const float* ssrc = ss1;
    const int* cc = cnt; const int* sl = slt1; float* Z = Z1;
    if (blk >= NB1) { blk -= NB1; sdst = sd2; ssrc = ss2; cc = cnt + Nn; sl = slt2; Z = Z2; }
    int t = threadIdx.x;
    int lane = t & 63;
    int n = blk * 4 + (t >> 6);        // NB1*4 == Nn exactly; wave-uniform
    int deg = cc[n]; if (deg > PAD) deg = PAD;
    int hh = lane >> 3;
    int sub = lane & 7;
    float sd = sdst[n * 8 + hh];
    int sval = sl[n * PAD + (lane & 31)];
    const float4* h4 = (const float4*)h;

    float ssum = 0.f;
    float4 acc = make_float4(0.f, 0.f, 0.f, 0.f);

    int as0, as1, as2, as3;  float aa0, aa1, aa2, aa3;  float4 av0, av1, av2, av3;
    int bs0, bs1, bs2, bs3;  float ba0, ba1, ba2, ba3;  float4 bv0, bv1, bv2, bv3;

    LOADC(as0, as1, as2, as3, aa0, aa1, aa2, aa3, av0, av1, av2, av3, 0);
    int base = 0;
    for (;;) {
        int nxt = base + 4;
        bool more = nxt < deg;          // wave-uniform
        if (more) LOADC(bs0, bs1, bs2, bs3, ba0, ba1, ba2, ba3, bv0, bv1, bv2, bv3, nxt);
        CONS(aa0, aa1, aa2, aa3, av0, av1, av2, av3, base);
        if (!more) break;
        base = nxt;
        nxt = base + 4;
        more = nxt < deg;
        if (more) LOADC(as0, as1, as2, as3, aa0, aa1, aa2, aa3, av0, av1, av2, av3, nxt);
        CONS(ba0, ba1, ba2, ba3, bv0, bv1, bv2, bv3, base);
        if (!more) break;
        base = nxt;
    }

    float inv = 1.f / ssum;
    float4 o;
    o.x = acc.x * inv; o.y = acc.y * inv; o.z = acc.z * inv; o.w = acc.w * inv;
    o.x = o.x > 0.f ? o.x : __expf(o.x) - 1.f;
    o.y = o.y > 0.f ? o.y : __expf(o.y) - 1.f;
    o.z = o.z > 0.f ? o.z : __expf(o.z) - 1.f;
    o.w = o.w > 0.f ? o.w : __expf(o.w) - 1.f;
    ((float4*)Z)[(size_t)n * 64 + lane] = o;
}

__device__ __forceinline__ float fast_tanh(float x) {
    return 1.f - 2.f / (1.f + __expf(2.f * x));
}

// byte-offset XOR swizzle within a 1KB row (bits 4..6 <- row&7)
#define SWZ(off, r) ((off) ^ (((r) & 7) << 4))

// K5 v5: MFMA score with global_load_lds A-staging (zero-VGPR in-flight loads).
__global__ __launch_bounds__(256) void k_score(const float* __restrict__ Z1,
                        const float* __restrict__ Z2,
                        const short* __restrict__ fcwb,
                        const float* __restrict__ fcb,
                        const float* __restrict__ q,
                        float* __restrict__ Sacc) {
    __shared__ float zst[4 * 4096];    // 16 KB per wave, 64 KB total
    int t = threadIdx.x;
    int lane = t & 63;
    int wid = t >> 6;
    int task = blockIdx.x * 4 + wid;   // 0..NTASK-1, grid exact
    const float* Z = Z1; float* bins = Sacc;
    int tile = task;
    if (task >= NTASK / 2) { Z = Z2; bins = Sacc + 256; tile = task - NTASK / 2; }
    int nodebase = tile * 16;
    float* myst = &zst[wid * 4096];

    // ---- stage 16 rows x 1KB, LDS linear, global source pre-swizzled ----
    const char* zb = (const char*)(Z + (size_t)nodebase * Cc);
#pragma unroll
    for (int r = 0; r < 16; ++r) {
        const char* src = zb + r * 1024 + SWZ(lane * 16, r);
        __builtin_amdgcn_global_load_lds(
            (const __attribute__((address_space(1))) void*)src,
            (__attribute__((address_space(3))) void*)(myst + r * 256),
            16, 0, 0);
    }
    asm volatile("s_waitcnt vmcnt(0)" ::: "memory");
    __builtin_amdgcn_sched_barrier(0);

    int col = lane & 15;
    int quad = lane >> 4;

    // ---- read + convert 8 A-fragments from swizzled LDS ----
    const char* rowp = (const char*)myst + col * 1024;
    bf16x8 af[8];
#pragma unroll
    for (int ks = 0; ks < 8; ++ks) {
        int b0 = ks * 128 + quad * 32;
        float4 f0 = *(const float4*)(rowp + SWZ(b0, col));
        float4 f1 = *(const float4*)(rowp + SWZ(b0 + 16, col));
        bf16x8 a;
        a[0] = f2bf(f0.x); a[1] = f2bf(f0.y); a[2] = f2bf(f0.z); a[3] = f2bf(f0.w);
        a[4] = f2bf(f1.x); a[5] = f2bf(f1.y); a[6] = f2bf(f1.z); a[7] = f2bf(f1.w);
        af[ks] = a;
    }

    f32x4 acc[8];
#pragma unroll
    for (int tt = 0; tt < 8; ++tt) { acc[tt][0] = 0.f; acc[tt][1] = 0.f; acc[tt][2] = 0.f; acc[tt][3] = 0.f; }

    const short* brow = fcwb + (size_t)col * Cc + quad * 8;
#pragma unroll
    for (int ks = 0; ks < 8; ++ks) {
        bf16x8 bf[8];
#pragma unroll
        for (int tt = 0; tt < 8; ++tt)
            bf[tt] = *(const bf16x8*)(brow + tt * 4096 + ks * 32);
#pragma unroll
        for (int tt = 0; tt < 8; ++tt)
            acc[tt] = __builtin_amdgcn_mfma_f32_16x16x32_bf16(af[ks], bf[tt], acc[tt], 0, 0, 0);
    }

    float local = 0.f;
#pragma unroll
    for (int tt = 0; tt < 8; ++tt) {
        int sem = tt * 16 + col;
        float b = fcb[sem], qq = q[sem];
#pragma unroll
        for (int r = 0; r < 4; ++r) local += fast_tanh(acc[tt][r] + b) * qq;
    }
#pragma unroll
    for (int off = 32; off > 0; off >>= 1) local += __shfl_down(local, off);
    if (lane == 0) atomicAdd(&bins[(task & 31) * 8], local);
}

// K7: out = V0*out + V1*Z2; V from 32+32 score bins (stride-8 layout).
__global__ __launch_bounds__(256) void k_combine(float* __restrict__ out,
                                                 const float* __restrict__ Z2,
                                                 const float* __restrict__ S) {
    float s1 = 0.f, s2 = 0.f;
#pragma unroll
    for (int i = 0; i < 32; ++i) { s1 += S[i * 8]; s2 += S[256 + i * 8]; }
    s1 *= (1.f / (float)Nn);
    s2 *= (1.f / (float)Nn);
    float mx = fmaxf(s1, s2);
    float e1 = __expf(s1 - mx), e2 = __expf(s2 - mx);
    float inv = 1.f / (e1 + e2);
    float V0 = e1 * inv, V1 = e2 * inv;
    size_t i = (size_t)blockIdx.x * 256 + threadIdx.x;
    if (i < (size_t)Nn * 64) {
        float4 a = ((float4*)out)[i];
        float4 b = ((const float4*)Z2)[i];
        a.x = V0 * a.x + V1 * b.x;
        a.y = V0 * a.y + V1 * b.y;
        a.z = V0 * a.z + V1 * b.z;
        a.w = V0 * a.w + V1 * b.w;
        ((float4*)out)[i] = a;
    }
}

extern "C" void kernel_launch(void* const* d_in, const int* in_sizes, int n_in,
                              void* d_out, int out_size, void* d_ws, size_t ws_size,
                              hipStream_t stream) {
    const float* x    = (const float*)d_in[0];
    const float* W    = (const float*)d_in[1];
    const float* att1 = (const float*)d_in[2];
    const float* att2 = (const float*)d_in[3];
    const float* fcw  = (const float*)d_in[4];
    const float* fcb  = (const float*)d_in[5];
    const float* q    = (const float*)d_in[6];
    const int*   ei1  = (const int*)d_in[7];
    const int*   ei2  = (const int*)d_in[8];
    int E1 = in_sizes[7] / 2;
    int E2 = in_sizes[8] / 2;
    float* out = (float*)d_out;

    char* ws = (char*)d_ws;
    size_t off = 0;
    auto alloc = [&](size_t bytes) -> char* {
        char* p = ws + off;
        off = (off + bytes + 255) & ~(size_t)255;
        return p;
    };
    float* Z2   = (float*)alloc((size_t)Nn * Cc * 4);
    float* h    = (float*)alloc((size_t)Nn * Dd * 4);
    float* sd1  = (float*)alloc((size_t)Nn * Hh * 4);
    float* ss1  = (float*)alloc((size_t)Nn * Hh * 4);
    float* sd2  = (float*)alloc((size_t)Nn * Hh * 4);
    float* ss2  = (float*)alloc((size_t)Nn * Hh * 4);
    int*   cnt  = (int*)alloc((size_t)2 * Nn * 4);
    float* red  = (float*)alloc(2048);         // 2 sets x 32 bins, stride 8 floats
    float* Wt   = (float*)alloc((size_t)Dd * Cc * 4);
    short* fcwb = (short*)alloc((size_t)SEMk * Cc * 2);
    int*   slt1 = (int*)alloc((size_t)Nn * PAD * 4);
    int*   slt2 = (int*)alloc((size_t)Nn * PAD * 4);
    (void)ws_size; (void)n_in; (void)out_size;

    hipMemsetAsync(cnt, 0, (size_t)2 * Nn * 4, stream);
    hipMemsetAsync(red, 0, 2048, stream);

    k_scatter<<<(E1 + E2 + 255) / 256, 256, 0, stream>>>(ei1, E1, ei2, E2, cnt, slt1, slt2,
                                                         W, Wt, fcw, fcwb);
    k_hproj<<<Nn / 32, 128, 0, stream>>>(x, Wt, att1, att2, h, sd1, ss1, sd2, ss2);
    k_gat<<<2 * NB1, 256, 0, stream>>>(h, sd1, ss1, sd2, ss2, cnt, slt1, slt2, out, Z2);
    k_score<<<NTASK / 4, 256, 0, stream>>>(out, Z2, fcwb, fcb, q, red);
    k_combine<<<(Nn * 64) / 256, 256, 0, stream>>>(out, Z2, red);
}